// Round 1
// baseline (1500.455 us; speedup 1.0000x reference)
//
#include <hip/hip_runtime.h>
#include <hip/hip_bf16.h>
#include <math.h>

#define B_   64
#define T_   512
#define F_   256
#define ENC_ 256
#define P_   128
#define H_   256
#define K_   12
#define INV_TEMP 10.0f

typedef unsigned short u16;
typedef _Float16 half2v __attribute__((ext_vector_type(2)));
union U2H { unsigned int u; half2v h; };
typedef __attribute__((ext_vector_type(8))) short bf16x8;   // 8 bf16 = 4 VGPRs
typedef __attribute__((ext_vector_type(4))) float f32x4;    // MFMA C/D
typedef _Float16 f16x8 __attribute__((ext_vector_type(8))); // 8 f16 = 4 VGPRs
union BF8 { bf16x8 v; u16 e[8]; };

// ---------------- helpers ----------------------------------------------------
__device__ __forceinline__ float rcpf(float x) {
#if __has_builtin(__builtin_amdgcn_rcpf)
    return __builtin_amdgcn_rcpf(x);
#else
    return 1.f / x;
#endif
}
__device__ __forceinline__ u16 f2bf(float f) {   // RNE
    unsigned int u = __float_as_uint(f);
    unsigned int r = (u + 0x7fffu + ((u >> 16) & 1u)) >> 16;
    return (u16)r;
}
__device__ __forceinline__ float bf2f(u16 v) {
    return __uint_as_float(((unsigned int)v) << 16);
}
__device__ __forceinline__ float bflo(unsigned int u) { return __uint_as_float(u << 16); }
__device__ __forceinline__ float bfhi(unsigned int u) { return __uint_as_float(u & 0xffff0000u); }
__device__ __forceinline__ float wave_sum(float v) {
    #pragma unroll
    for (int o = 32; o > 0; o >>= 1) v += __shfl_down(v, o, 64);
    return v;
}

// ---------------- merged setup: weight conversions + fold + accum zero -------
// blocks 0..191: Wh -> Wht f16 (transposed, [768][256] = MFMA B^T layout);
// 192..287: Wi -> Wit bf16 (transposed); 288..671: Wp -> Wpt bf16 (transposed);
// 672..800: fold (Wct, bc, accum=0)
__global__ __launch_bounds__(256) void setup_conv(const float* __restrict__ Wh,
                                                  _Float16* __restrict__ Wht,
                                                  const float* __restrict__ Wi,
                                                  u16* __restrict__ Wit,
                                                  const float* __restrict__ Wp,
                                                  u16* __restrict__ Wpt,
                                                  const float* __restrict__ We,
                                                  const float* __restrict__ be,
                                                  const float* __restrict__ Wpj,
                                                  const float* __restrict__ bpj,
                                                  u16* __restrict__ Wct,
                                                  float* __restrict__ bc,
                                                  float* __restrict__ accum) {
    int bid = blockIdx.x;
    if (bid < 192) {
        // Wht[g][k] = (f16)Wh[k][g]  (768x256 out of 256x768 in; 24x8 32x32 tiles)
        __shared__ float tile0[32][33];
        int g0 = (bid % 24) * 32, k0 = (bid / 24) * 32;
        int tx = threadIdx.x & 31, ty = threadIdx.x >> 5;
        #pragma unroll
        for (int i = 0; i < 32; i += 8)
            tile0[ty + i][tx] = Wh[(size_t)(k0 + ty + i) * 768 + g0 + tx];
        __syncthreads();
        #pragma unroll
        for (int i = 0; i < 32; i += 8)
            Wht[(size_t)(g0 + ty + i) * 256 + k0 + tx] = (_Float16)tile0[tx][ty + i];
    } else if (bid < 288) {
        __shared__ float tile[32][33];
        int b2 = bid - 192;                       // 0..95
        int n0 = (b2 % 24) * 32, k0 = (b2 / 24) * 32;
        int tx = threadIdx.x & 31, ty = threadIdx.x >> 5;
        #pragma unroll
        for (int i = 0; i < 32; i += 8)
            tile[ty + i][tx] = Wi[(size_t)(k0 + ty + i) * 768 + n0 + tx];
        __syncthreads();
        #pragma unroll
        for (int i = 0; i < 32; i += 8)
            Wit[(size_t)(n0 + ty + i) * 128 + k0 + tx] = f2bf(tile[tx][ty + i]);
    } else if (bid < 672) {
        __shared__ float tile2[32][33];
        int b3 = bid - 288;                       // 0..383
        int kq = b3 / 32, rem = b3 % 32;
        int h0 = (rem % 8) * 32, p0 = (rem / 8) * 32;
        int tx = threadIdx.x & 31, ty = threadIdx.x >> 5;
        #pragma unroll
        for (int i = 0; i < 32; i += 8)
            tile2[ty + i][tx] = Wp[(size_t)kq * H_ * P_ + (size_t)(h0 + ty + i) * P_ + p0 + tx];
        __syncthreads();
        #pragma unroll
        for (int i = 0; i < 32; i += 8)
            Wpt[(size_t)kq * P_ * H_ + (size_t)(p0 + ty + i) * H_ + h0 + tx] = f2bf(tile2[tx][ty + i]);
    } else {
        // fold: f = 2*(bid-672) + (tid>>7); p = tid&127
        int f = (bid - 672) * 2 + (threadIdx.x >> 7);
        int p = threadIdx.x & 127;
        if (f < F_) {
            float a = 0.f;
            for (int e = 0; e < ENC_; e++) a = fmaf(We[f * ENC_ + e], Wpj[e * P_ + p], a);
            Wct[(size_t)p * F_ + f] = f2bf(a);
        } else if (f == F_) {
            float a = bpj[p];
            for (int e = 0; e < ENC_; e++) a = fmaf(be[e], Wpj[e * P_ + p], a);
            bc[p] = a;
        } else {
            #pragma unroll
            for (int i = 0; i < 8; i++) accum[p * 8 + i] = 0.f;
        }
    }
}

// ---------------- MFMA GEMM, A = fp32 (converted in-register) ----------------
__global__ __launch_bounds__(256) void gemm_mfma_f32a(const float* __restrict__ A,
                                                      const u16* __restrict__ Bt,
                                                      const float* __restrict__ bias,
                                                      u16* __restrict__ Ch,
                                                      int N, int K) {
    int tid  = threadIdx.x;
    int w    = tid >> 6;
    int lane = tid & 63;
    int col  = lane & 15;
    int quad = lane >> 4;
    int bm = blockIdx.y * 64, bn = blockIdx.x * 128;

    f32x4 acc[8] = {};
    const float* arow = A + (size_t)(bm + w * 16 + col) * K;
    #pragma unroll
    for (int k0 = 0; k0 < K; k0 += 32) {
        float4 v0 = *(const float4*)(arow + k0 + quad * 8);
        float4 v1 = *(const float4*)(arow + k0 + quad * 8 + 4);
        BF8 af;
        af.e[0] = f2bf(v0.x); af.e[1] = f2bf(v0.y); af.e[2] = f2bf(v0.z); af.e[3] = f2bf(v0.w);
        af.e[4] = f2bf(v1.x); af.e[5] = f2bf(v1.y); af.e[6] = f2bf(v1.z); af.e[7] = f2bf(v1.w);
        #pragma unroll
        for (int nt = 0; nt < 8; nt++) {
            bf16x8 bf = *(const bf16x8*)(Bt + (size_t)(bn + nt * 16 + col) * K + k0 + quad * 8);
            acc[nt] = __builtin_amdgcn_mfma_f32_16x16x32_bf16(af.v, bf, acc[nt], 0, 0, 0);
        }
    }
    #pragma unroll
    for (int nt = 0; nt < 8; nt++) {
        int gn = bn + nt * 16 + col;
        float bv = bias[gn];
        #pragma unroll
        for (int r = 0; r < 4; r++) {
            int gm = bm + w * 16 + quad * 4 + r;
            Ch[(size_t)gm * N + gn] = f2bf(acc[nt][r] + bv);
        }
    }
}

// ---------------- MFMA GEMM, A = bf16, C = bf16 ------------------------------
__global__ __launch_bounds__(256) void gemm_mfma(const u16* __restrict__ A,
                                                 const u16* __restrict__ Bt,
                                                 const float* __restrict__ bias,
                                                 u16* __restrict__ Ch,
                                                 int N, int K) {
    int tid  = threadIdx.x;
    int w    = tid >> 6;
    int lane = tid & 63;
    int col  = lane & 15;
    int quad = lane >> 4;
    int bm = blockIdx.y * 64, bn = blockIdx.x * 128;

    f32x4 acc[8] = {};
    const u16* arow = A + (size_t)(bm + w * 16 + col) * K;
    #pragma unroll
    for (int k0 = 0; k0 < K; k0 += 32) {
        bf16x8 af = *(const bf16x8*)(arow + k0 + quad * 8);
        #pragma unroll
        for (int nt = 0; nt < 8; nt++) {
            bf16x8 bf = *(const bf16x8*)(Bt + (size_t)(bn + nt * 16 + col) * K + k0 + quad * 8);
            acc[nt] = __builtin_amdgcn_mfma_f32_16x16x32_bf16(af, bf, acc[nt], 0, 0, 0);
        }
    }
    #pragma unroll
    for (int nt = 0; nt < 8; nt++) {
        int gn = bn + nt * 16 + col;
        float bv = bias[gn];
        #pragma unroll
        for (int r = 0; r < 4; r++) {
            int gm = bm + w * 16 + quad * 4 + r;
            Ch[(size_t)gm * N + gn] = f2bf(acc[nt][r] + bv);
        }
    }
}

// ---------------- GRU scan (blocks 0..3, MFMA, 16 batches/block)
//                + zsum (blocks 4..67) ---------------------------------------
// MFMA rewrite: h@Wh on the matrix pipe. Block = 16 batches = one M=16 tile.
// Wave w owns h-cols [32w,32w+32) for all 3 gates -> (r,z,n) for a given
// (batch,j) land in ONE lane's accumulators -> activations fully in-register.
// Wh^T slice resident in 192 regs/lane (AGPR-eligible, MFMA reads AGPRs).
// h double-buffered in LDS (1 barrier/t); gi async-staged via global_load_lds
// double buffer (barrier's vmcnt drain is the completion guarantee).
#define GRUB_ 4
#define BPB_  16

__global__ __attribute__((amdgpu_flat_work_group_size(512, 512), amdgpu_waves_per_eu(2, 2)))
void gru_zsum_kernel(const u16* __restrict__ gi,
                     const _Float16* __restrict__ Wht,
                     const float* __restrict__ bhn,
                     u16* __restrict__ ch,
                     const u16* __restrict__ zh,
                     float* __restrict__ zsum) {
    __shared__ __align__(16) char smem[66048];
    int tid = threadIdx.x;          // 0..511

    if (blockIdx.x >= GRUB_) {
        // ---- zsum[b][p] = sum_{t=1..T-1} z[b][t][p], 16-way t-split ---------
        float (*part)[128] = (float (*)[128])smem;   // 8192 B
        int b   = blockIdx.x - GRUB_;
        int pg  = tid & 31;
        int g   = tid >> 5;
        const u16* zb = zh + (size_t)b * T_ * P_;
        float s0 = 0.f, s1 = 0.f, s2 = 0.f, s3 = 0.f;
        for (int t = 1 + g; t < T_; t += 16) {
            uint2 v = *(const uint2*)(zb + (size_t)t * P_ + pg * 4);
            s0 += bflo(v.x); s1 += bfhi(v.x);
            s2 += bflo(v.y); s3 += bfhi(v.y);
        }
        part[g][pg * 4 + 0] = s0; part[g][pg * 4 + 1] = s1;
        part[g][pg * 4 + 2] = s2; part[g][pg * 4 + 3] = s3;
        __syncthreads();
        if (tid < 128) {
            float s = 0.f;
            #pragma unroll
            for (int g2 = 0; g2 < 16; g2++) s += part[g2][tid];
            zsum[(size_t)b * P_ + tid] = s;
        }
        return;
    }

    // ---- GRU ----------------------------------------------------------------
    _Float16 (*hb)[16][264] = (_Float16 (*)[16][264])smem;        // 2 x 8448 B (+8 f16 pad)
    u16 (*gils)[16][768]    = (u16 (*)[16][768])(smem + 16896);   // 2 x 24576 B

    int lane = tid & 63, w = tid >> 6;
    int col  = lane & 15, quad = lane >> 4;
    int bb   = blockIdx.x * BPB_;
    int jj0  = w * 32 + col;                     // n2=0 gate-col; n2=1 adds 16

    // B fragments: wf[gate][n2][k0] = Wht[gcol][k0*32 + quad*8 .. +7]
    f16x8 wf[3][2][8];
    #pragma unroll
    for (int g = 0; g < 3; g++)
        #pragma unroll
        for (int n2 = 0; n2 < 2; n2++) {
            const _Float16* src = Wht + (size_t)(g * 256 + jj0 + n2 * 16) * 256 + quad * 8;
            #pragma unroll
            for (int k0 = 0; k0 < 8; k0++)
                wf[g][n2][k0] = *(const f16x8*)(src + k0 * 32);
        }
    // pin: make the asm the value source so the compiler can't re-load from
    // global inside the t-loop (same trick as the dot2 version used).
    #pragma unroll
    for (int g = 0; g < 3; g++)
        #pragma unroll
        for (int n2 = 0; n2 < 2; n2++)
            #pragma unroll
            for (int k0 = 0; k0 < 8; k0++)
                asm volatile("" : "+v"(wf[g][n2][k0]));

    for (int i = tid; i < 2 * 16 * 264; i += 512) ((_Float16*)hb)[i] = (_Float16)0.f;

    // gi staging: 16 batches x 768 bf16 = 24 KB/tile; 3 rounds x 512 thr x 16 B
    const u16* gp[3];
    #pragma unroll
    for (int rr = 0; rr < 3; rr++) {
        int off = (rr * 512 + tid) * 8;          // u16 index in the 16x768 tile
        int bt = off / 768, bo = off - bt * 768; // never crosses a row (768%8==0)
        gp[rr] = gi + (size_t)(bb + bt) * T_ * 768 + bo;
    }
    #pragma unroll
    for (int rr = 0; rr < 3; rr++) {             // stage t=0 into buf 0
        __builtin_amdgcn_global_load_lds(
            (const __attribute__((address_space(1))) void*)gp[rr],
            (__attribute__((address_space(3))) void*)(&gils[0][0][0] + (rr * 512 + w * 64) * 8),
            16, 0, 0);
        gp[rr] += 768;
    }

    float bh0 = bhn[jj0], bh1 = bhn[jj0 + 16];
    float hold[2][4] = {};
    u16* chp0 = ch + (size_t)(bb + quad * 4) * T_ * 256 + jj0;

    __syncthreads();   // drains vmcnt (t=0 staging) + lgkm (hb zeros)

    int cur = 0;
    #pragma unroll 1
    for (int t = 0; t < T_; t++) {
        int nxt = cur ^ 1;
        // stage gi(t+1) into the other buffer (async; end-of-t barrier drains)
        if (t + 1 < T_) {
            #pragma unroll
            for (int rr = 0; rr < 3; rr++) {
                __builtin_amdgcn_global_load_lds(
                    (const __attribute__((address_space(1))) void*)gp[rr],
                    (__attribute__((address_space(3))) void*)(&gils[nxt][0][0] + (rr * 512 + w * 64) * 8),
                    16, 0, 0);
                gp[rr] += 768;
            }
        }
        // gh = h(t-1) @ Wh : 48 MFMA (3 gates x 2 col-tiles x 8 K-tiles)
        f32x4 acc[3][2] = {};
        #pragma unroll
        for (int k0 = 0; k0 < 8; k0++) {
            f16x8 af = *(const f16x8*)(&hb[cur][col][k0 * 32 + quad * 8]);
            #pragma unroll
            for (int g = 0; g < 3; g++)
                #pragma unroll
                for (int n2 = 0; n2 < 2; n2++)
                    acc[g][n2] = __builtin_amdgcn_mfma_f32_16x16x32_f16(af, wf[g][n2][k0], acc[g][n2], 0, 0, 0);
        }
        // activations fully in-register per C-fragment lane:
        // lane owns (b = quad*4+r, j = jj0 + n2*16), r/z/n in acc[0..2][n2][r]
        int tof = t * 256;
        #pragma unroll
        for (int n2 = 0; n2 < 2; n2++) {
            int jj = jj0 + n2 * 16;
            float bh = n2 ? bh1 : bh0;
            #pragma unroll
            for (int r = 0; r < 4; r++) {
                int b = quad * 4 + r;
                float ir  = bf2f(gils[cur][b][jj]);
                float iz  = bf2f(gils[cur][b][256 + jj]);
                float inn = bf2f(gils[cur][b][512 + jj]);
                float rg  = rcpf(1.f + __expf(-(ir + acc[0][n2][r])));
                float zg  = rcpf(1.f + __expf(-(iz + acc[1][n2][r])));
                float xn  = inn + rg * (acc[2][n2][r] + bh);
                float nn  = fmaf(2.f, rcpf(1.f + __expf(-2.f * xn)), -1.f);
                float hv  = (1.f - zg) * nn + zg * hold[n2][r];
                hold[n2][r] = hv;
                hb[nxt][b][jj] = (_Float16)hv;
                chp0[r * (T_ * 256) + tof + n2 * 16] = f2bf(hv);
            }
        }
        __syncthreads();   // h(t) + gi(t+1) visible; flips buffers
        cur = nxt;
    }
}

// ---------------- fused loss, MFMA; 128-row tiles; zh tiles staged in LDS ----
__global__ __launch_bounds__(512) void loss_fused(const u16* __restrict__ ch,
                                                  const u16* __restrict__ Wpt,
                                                  const float* __restrict__ bp,
                                                  const u16* __restrict__ zh,
                                                  const float* __restrict__ zsum,
                                                  float* __restrict__ accum) {
    __shared__ u16 Pst[128][136];
    __shared__ u16 Zt[64][136];
    __shared__ float sS[128];
    __shared__ float red[8];
    int k  = blockIdx.z + 1;
    int b  = blockIdx.y;
    int t0 = blockIdx.x * 128;
    int Tk = T_ - k;
    int tid  = threadIdx.x;
    int w    = tid >> 6;
    int lane = tid & 63;
    int col  = lane & 15;
    int quad = lane >> 4;
    const u16* zb = zh + (size_t)b * T_ * P_;

    // S_bk = zsum_b - sum_{t=1}^{k-1} z[t]
    if (tid < 128) {
        float s = zsum[(size_t)b * P_ + tid];
        for (int t = 1; t < k; t++) s -= bf2f(zb[(size_t)t * P_ + tid]);
        sS[tid] = s;
    }

    // ---- phase 1: Pst = bf16(ch-tile @ Wp[k] + bp[k]) -----------------------
    {
        f32x4 acc[8] = {};
        const u16* arow = ch + ((size_t)b * T_ + t0 + w * 16 + col) * H_;
        const u16* wk   = Wpt + (size_t)(k - 1) * P_ * H_;
        #pragma unroll
        for (int k0 = 0; k0 < 8; k0++) {
            bf16x8 af = *(const bf16x8*)(arow + k0 * 32 + quad * 8);
            #pragma unroll
            for (int nt = 0; nt < 8; nt++) {
                bf16x8 bf = *(const bf16x8*)(wk + (size_t)(nt * 16 + col) * H_ + k0 * 32 + quad * 8);
                acc[nt] = __builtin_amdgcn_mfma_f32_16x16x32_bf16(af, bf, acc[nt], 0, 0, 0);
            }
        }
        #pragma unroll
        for (int nt = 0; nt < 8; nt++) {
            float bias = bp[(size_t)(k - 1) * P_ + nt * 16 + col];
            #pragma unroll
            for (int r = 0; r < 4; r++)
                Pst[w * 16 + quad * 4 + r][nt * 16 + col] = f2bf(acc[nt][r] + bias);
        }
    }
    __syncthreads();

    // ---- phase 2: flash LSE over LDS-staged zh tiles ------------------------
    float mloc[4], sloc[4];
    #pragma unroll
    for (int r = 0; r < 4; r++) { mloc[r] = -INFINITY; sloc[r] = 0.f; }

    for (int ct = 0; ct < Tk; ct += 64) {
        __syncthreads();             // Zt free (prev tile's MFMAs done)
        {
            // 64 rows x 256 B = 16 KB contiguous; 512 thr x 2 x 16 B, coalesced
            int cc = tid;
            #pragma unroll
            for (int rep = 0; rep < 2; rep++, cc += 512) {
                int row = cc >> 4;
                int off = (cc & 15) * 8;
                int tcol = k + ct + row;     // may over-read into slack (masked)
                *(uint4*)&Zt[row][off] = *(const uint4*)(zb + (size_t)tcol * P_ + off);
            }
        }
        __syncthreads();
        f32x4 acc[4] = {};
        #pragma unroll
        for (int k0 = 0; k0 < 4; k0++) {
            bf16x8 af = *(const bf16x8*)(&Pst[w * 16 + col][k0 * 32 + quad * 8]);
            #pragma unroll
            for (int nt = 0; nt < 4; nt++) {
                bf16x8 bf = *(const bf16x8*)(&Zt[nt * 16 + col][k0 * 32 + quad * 8]);
                acc[nt] = __builtin_amdgcn_mfma_f32_16x16x32_bf16(af, bf, acc[nt], 0, 0, 0);
            }
        }
        #pragma unroll
        for (int r = 0; r < 4; r++) {
            float l[4];
            float tmax = -INFINITY;
            #pragma unroll
            for (int nt = 0; nt < 4; nt++) {
                bool valid = (ct + nt * 16 + col) < Tk;
                l[nt] = valid ? acc[nt][r] * INV_TEMP : -INFINITY;
                tmax = fmaxf(tmax, l[nt]);
            }
            float mnew = fmaxf(mloc[r], tmax);
            float e = __expf(l[0] - mnew) + __expf(l[1] - mnew)
                    + __expf(l[2] - mnew) + __expf(l[3] - mnew);
            sloc[r] = sloc[r] * __expf(mloc[r] - mnew) + e;
            mloc[r] = mnew;
        }
    }
    #pragma unroll
    for (int r = 0; r < 4; r++) {
        #pragma unroll
        for (int o = 1; o < 16; o <<= 1) {
            float mo = __shfl_xor(mloc[r], o, 64);
            float so = __shfl_xor(sloc[r], o, 64);
            float mn = fmaxf(mloc[r], mo);
            sloc[r] = sloc[r] * __expf(mloc[r] - mn) + so * __expf(mo - mn);
            mloc[r] = mn;
        }
    }
    float tkinv = INV_TEMP / (float)Tk;
    float scale = 1.0f / ((float)K_ * (float)B_ * (float)Tk);
    float bs = 0.f;
    #pragma unroll
    for (int r = 0; r < 4; r++) {
        int row = w * 16 + quad * 4 + r;
        BF8 pv;
        pv.v = *(const bf16x8*)(&Pst[row][col * 8]);
        float d = 0.f;
        #pragma unroll
        for (int m = 0; m < 8; m++) d = fmaf(bf2f(pv.e[m]), sS[col * 8 + m], d);
        #pragma unroll
        for (int o = 1; o < 16; o <<= 1) d += __shfl_xor(d, o, 64);
        int gr = t0 + row;
        if (gr < Tk) bs += mloc[r] + __logf(sloc[r]) - d * tkinv;
    }
    if (col != 0) bs = 0.f;
    bs = wave_sum(bs);
    if (lane == 0) red[w] = bs;
    __syncthreads();
    if (tid == 0) {
        float tot = 0.f;
        #pragma unroll
        for (int i = 0; i < 8; i++) tot += red[i];
        atomicAdd(&accum[(blockIdx.x * 809 + b * 67 + blockIdx.z * 131) & 1023],
                  tot * scale);
    }
}

__global__ void finalize(const float* __restrict__ accum, float* __restrict__ out) {
    int tid = threadIdx.x;
    __shared__ float red[4];
    float v = 0.f;
    for (int i = tid; i < 1024; i += 256) v += accum[i];
    float sres = wave_sum(v);
    if ((tid & 63) == 0) red[tid >> 6] = sres;
    __syncthreads();
    if (tid == 0) out[0] = red[0] + red[1] + red[2] + red[3];
}

// ---------------- launch -----------------------------------------------------
extern "C" void kernel_launch(void* const* d_in, const int* in_sizes, int n_in,
                              void* d_out, int out_size, void* d_ws, size_t ws_size,
                              hipStream_t stream) {
    const float* x      = (const float*)d_in[0];
    const float* W_enc  = (const float*)d_in[1];
    const float* b_enc  = (const float*)d_in[2];
    const float* W_proj = (const float*)d_in[3];
    const float* b_proj = (const float*)d_in[4];
    const float* Wi     = (const float*)d_in[5];
    const float* bi     = (const float*)d_in[6];
    const float* Wh     = (const float*)d_in[7];
    const float* bhn    = (const float*)d_in[8];
    const float* Wp     = (const float*)d_in[9];
    const float* bp     = (const float*)d_in[10];
    float* out = (float*)d_out;

    // layout (float offsets)
    float* ws    = (float*)d_ws;
    float* bc    = ws;                          // 128
    float* accum = bc + 128;                    // 1024 -> end 1152
    _Float16* Wht = (_Float16*)(ws + 1152);     // 196608 f16 = 98304 fl -> end 99456
    u16* Wct     = (u16*)(ws + 99456);          // 16384 fl -> end 115840
    u16* Wit     = (u16*)(ws + 115840);         // 49152 fl -> end 164992
    u16* Wpt     = (u16*)(ws + 164992);         // 196608 fl -> end 361600
    u16* zh      = (u16*)(ws + 361600);         // 2097152 fl -> end 2458752
    float* zsum  = ws + 2458752;                // 8192 fl (doubles as zh over-read slack) -> end 2466944
    u16* gi      = (u16*)(ws + 2466944);        // 12582912 fl -> end 15049856
    u16* ch      = (u16*)(ws + 15049856);       // 4194304 fl -> end 19244160 (~77 MB)

    const int MT = B_ * T_;                     // 32768

    // merged setup: all weight conversions + fold + accum zero (801 blocks)
    setup_conv<<<801, 256, 0, stream>>>(Wh, Wht, Wi, Wit, Wp, Wpt,
                                        W_enc, b_enc, W_proj, b_proj, Wct, bc, accum);
    // zh = bf16(x @ Wct^T + bc)   (M=32768, N=128, K=256; A converted in-reg)
    gemm_mfma_f32a<<<dim3(1, MT / 64), 256, 0, stream>>>(x, Wct, bc, zh, P_, F_);
    // gi = bf16(zh @ Wit^T + bi)  (M=32768, N=768, K=128)
    gemm_mfma<<<dim3(6, MT / 64), 256, 0, stream>>>(zh, Wit, bi, gi, 3 * H_, P_);
    // GRU scan, MFMA, 16 batches/block (blocks 0..3) + zsum (blocks 4..67)
    gru_zsum_kernel<<<GRUB_ + B_, 512, 0, stream>>>(gi, Wht, bhn, ch, zh, zsum);
    // fused pred-GEMM + flash loss (MFMA), 128-row tiles, LDS-staged zh
    loss_fused<<<dim3(4, B_, K_), 512, 0, stream>>>(ch, Wpt, bp, zh, zsum, accum);
    finalize<<<1, 256, 0, stream>>>(accum, out);
}

// Round 2
// 953.592 us; speedup vs baseline: 1.5735x; 1.5735x over previous
//
#include <hip/hip_runtime.h>
#include <hip/hip_bf16.h>
#include <math.h>

#define B_   64
#define T_   512
#define F_   256
#define ENC_ 256
#define P_   128
#define H_   256
#define K_   12
#define INV_TEMP 10.0f

typedef unsigned short u16;
typedef _Float16 half2v __attribute__((ext_vector_type(2)));
union U2H { unsigned int u; half2v h; };
typedef __attribute__((ext_vector_type(8))) short bf16x8;   // 8 bf16 = 4 VGPRs
typedef __attribute__((ext_vector_type(4))) float f32x4;    // MFMA C/D
typedef _Float16 f16x8 __attribute__((ext_vector_type(8))); // 8 f16 = 4 VGPRs
union BF8 { bf16x8 v; u16 e[8]; };

// ---------------- helpers ----------------------------------------------------
__device__ __forceinline__ float rcpf(float x) {
#if __has_builtin(__builtin_amdgcn_rcpf)
    return __builtin_amdgcn_rcpf(x);
#else
    return 1.f / x;
#endif
}
__device__ __forceinline__ u16 f2bf(float f) {   // RNE
    unsigned int u = __float_as_uint(f);
    unsigned int r = (u + 0x7fffu + ((u >> 16) & 1u)) >> 16;
    return (u16)r;
}
__device__ __forceinline__ float bf2f(u16 v) {
    return __uint_as_float(((unsigned int)v) << 16);
}
__device__ __forceinline__ float bflo(unsigned int u) { return __uint_as_float(u << 16); }
__device__ __forceinline__ float bfhi(unsigned int u) { return __uint_as_float(u & 0xffff0000u); }
__device__ __forceinline__ float wave_sum(float v) {
    #pragma unroll
    for (int o = 32; o > 0; o >>= 1) v += __shfl_down(v, o, 64);
    return v;
}

// ---------------- merged setup: weight conversions + fold + accum zero -------
// blocks 0..191: Wh -> Wht f16 (transposed, [768][256] = MFMA B^T layout);
// 192..287: Wi -> Wit bf16 (transposed); 288..671: Wp -> Wpt bf16 (transposed);
// 672..800: fold (Wct, bc, accum=0)
__global__ __launch_bounds__(256) void setup_conv(const float* __restrict__ Wh,
                                                  _Float16* __restrict__ Wht,
                                                  const float* __restrict__ Wi,
                                                  u16* __restrict__ Wit,
                                                  const float* __restrict__ Wp,
                                                  u16* __restrict__ Wpt,
                                                  const float* __restrict__ We,
                                                  const float* __restrict__ be,
                                                  const float* __restrict__ Wpj,
                                                  const float* __restrict__ bpj,
                                                  u16* __restrict__ Wct,
                                                  float* __restrict__ bc,
                                                  float* __restrict__ accum) {
    int bid = blockIdx.x;
    if (bid < 192) {
        // Wht[g][k] = (f16)Wh[k][g]  (768x256 out of 256x768 in; 24x8 32x32 tiles)
        __shared__ float tile0[32][33];
        int g0 = (bid % 24) * 32, k0 = (bid / 24) * 32;
        int tx = threadIdx.x & 31, ty = threadIdx.x >> 5;
        #pragma unroll
        for (int i = 0; i < 32; i += 8)
            tile0[ty + i][tx] = Wh[(size_t)(k0 + ty + i) * 768 + g0 + tx];
        __syncthreads();
        #pragma unroll
        for (int i = 0; i < 32; i += 8)
            Wht[(size_t)(g0 + ty + i) * 256 + k0 + tx] = (_Float16)tile0[tx][ty + i];
    } else if (bid < 288) {
        __shared__ float tile[32][33];
        int b2 = bid - 192;                       // 0..95
        int n0 = (b2 % 24) * 32, k0 = (b2 / 24) * 32;
        int tx = threadIdx.x & 31, ty = threadIdx.x >> 5;
        #pragma unroll
        for (int i = 0; i < 32; i += 8)
            tile[ty + i][tx] = Wi[(size_t)(k0 + ty + i) * 768 + n0 + tx];
        __syncthreads();
        #pragma unroll
        for (int i = 0; i < 32; i += 8)
            Wit[(size_t)(n0 + ty + i) * 128 + k0 + tx] = f2bf(tile[tx][ty + i]);
    } else if (bid < 672) {
        __shared__ float tile2[32][33];
        int b3 = bid - 288;                       // 0..383
        int kq = b3 / 32, rem = b3 % 32;
        int h0 = (rem % 8) * 32, p0 = (rem / 8) * 32;
        int tx = threadIdx.x & 31, ty = threadIdx.x >> 5;
        #pragma unroll
        for (int i = 0; i < 32; i += 8)
            tile2[ty + i][tx] = Wp[(size_t)kq * H_ * P_ + (size_t)(h0 + ty + i) * P_ + p0 + tx];
        __syncthreads();
        #pragma unroll
        for (int i = 0; i < 32; i += 8)
            Wpt[(size_t)kq * P_ * H_ + (size_t)(p0 + ty + i) * H_ + h0 + tx] = f2bf(tile2[tx][ty + i]);
    } else {
        // fold: f = 2*(bid-672) + (tid>>7); p = tid&127
        int f = (bid - 672) * 2 + (threadIdx.x >> 7);
        int p = threadIdx.x & 127;
        if (f < F_) {
            float a = 0.f;
            for (int e = 0; e < ENC_; e++) a = fmaf(We[f * ENC_ + e], Wpj[e * P_ + p], a);
            Wct[(size_t)p * F_ + f] = f2bf(a);
        } else if (f == F_) {
            float a = bpj[p];
            for (int e = 0; e < ENC_; e++) a = fmaf(be[e], Wpj[e * P_ + p], a);
            bc[p] = a;
        } else {
            #pragma unroll
            for (int i = 0; i < 8; i++) accum[p * 8 + i] = 0.f;
        }
    }
}

// ---------------- MFMA GEMM, A = fp32 (converted in-register) ----------------
__global__ __launch_bounds__(256) void gemm_mfma_f32a(const float* __restrict__ A,
                                                      const u16* __restrict__ Bt,
                                                      const float* __restrict__ bias,
                                                      u16* __restrict__ Ch,
                                                      int N, int K) {
    int tid  = threadIdx.x;
    int w    = tid >> 6;
    int lane = tid & 63;
    int col  = lane & 15;
    int quad = lane >> 4;
    int bm = blockIdx.y * 64, bn = blockIdx.x * 128;

    f32x4 acc[8] = {};
    const float* arow = A + (size_t)(bm + w * 16 + col) * K;
    #pragma unroll
    for (int k0 = 0; k0 < K; k0 += 32) {
        float4 v0 = *(const float4*)(arow + k0 + quad * 8);
        float4 v1 = *(const float4*)(arow + k0 + quad * 8 + 4);
        BF8 af;
        af.e[0] = f2bf(v0.x); af.e[1] = f2bf(v0.y); af.e[2] = f2bf(v0.z); af.e[3] = f2bf(v0.w);
        af.e[4] = f2bf(v1.x); af.e[5] = f2bf(v1.y); af.e[6] = f2bf(v1.z); af.e[7] = f2bf(v1.w);
        #pragma unroll
        for (int nt = 0; nt < 8; nt++) {
            bf16x8 bf = *(const bf16x8*)(Bt + (size_t)(bn + nt * 16 + col) * K + k0 + quad * 8);
            acc[nt] = __builtin_amdgcn_mfma_f32_16x16x32_bf16(af.v, bf, acc[nt], 0, 0, 0);
        }
    }
    #pragma unroll
    for (int nt = 0; nt < 8; nt++) {
        int gn = bn + nt * 16 + col;
        float bv = bias[gn];
        #pragma unroll
        for (int r = 0; r < 4; r++) {
            int gm = bm + w * 16 + quad * 4 + r;
            Ch[(size_t)gm * N + gn] = f2bf(acc[nt][r] + bv);
        }
    }
}

// ---------------- MFMA GEMM, A = bf16, C = bf16 ------------------------------
__global__ __launch_bounds__(256) void gemm_mfma(const u16* __restrict__ A,
                                                 const u16* __restrict__ Bt,
                                                 const float* __restrict__ bias,
                                                 u16* __restrict__ Ch,
                                                 int N, int K) {
    int tid  = threadIdx.x;
    int w    = tid >> 6;
    int lane = tid & 63;
    int col  = lane & 15;
    int quad = lane >> 4;
    int bm = blockIdx.y * 64, bn = blockIdx.x * 128;

    f32x4 acc[8] = {};
    const u16* arow = A + (size_t)(bm + w * 16 + col) * K;
    #pragma unroll
    for (int k0 = 0; k0 < K; k0 += 32) {
        bf16x8 af = *(const bf16x8*)(arow + k0 + quad * 8);
        #pragma unroll
        for (int nt = 0; nt < 8; nt++) {
            bf16x8 bf = *(const bf16x8*)(Bt + (size_t)(bn + nt * 16 + col) * K + k0 + quad * 8);
            acc[nt] = __builtin_amdgcn_mfma_f32_16x16x32_bf16(af, bf, acc[nt], 0, 0, 0);
        }
    }
    #pragma unroll
    for (int nt = 0; nt < 8; nt++) {
        int gn = bn + nt * 16 + col;
        float bv = bias[gn];
        #pragma unroll
        for (int r = 0; r < 4; r++) {
            int gm = bm + w * 16 + quad * 4 + r;
            Ch[(size_t)gm * N + gn] = f2bf(acc[nt][r] + bv);
        }
    }
}

// ---------------- GRU scan (blocks 0..63, MFMA, 1 batch/block)
//                + zsum (blocks 64..127) -------------------------------------
// M=16 tile = 16 replicas of the single batch h-row (replication is free:
// the 384-MFMA/CU/t floor is set by gate cols x K, not batches). All C-rows
// identical -> activation uses acc[..][0] (static index), 2 triples/lane.
// gi: per-lane global ushort prefetch (1 step ahead), broadcast across quads
// -> one 32B segment per instr per wave. h: 264-f16 double-buffered LDS row,
// broadcast A-fragment reads (conflict-free). Raw s_barrier + lgkmcnt(0)
// (no vmcnt(0) drain of the in-flight prefetch).
#define GRUB_ 64

__global__ __attribute__((amdgpu_flat_work_group_size(512, 512)))
void gru_zsum_kernel(const u16* __restrict__ gi,
                     const _Float16* __restrict__ Wht,
                     const float* __restrict__ bhn,
                     u16* __restrict__ ch,
                     const u16* __restrict__ zh,
                     float* __restrict__ zsum) {
    __shared__ __align__(16) char smem[8704];
    int tid = threadIdx.x;          // 0..511

    if (blockIdx.x >= GRUB_) {
        // ---- zsum[b][p] = sum_{t=1..T-1} z[b][t][p], 16-way t-split ---------
        float (*part)[128] = (float (*)[128])smem;   // 8192 B
        int b   = blockIdx.x - GRUB_;
        int pg  = tid & 31;
        int g   = tid >> 5;
        const u16* zb = zh + (size_t)b * T_ * P_;
        float s0 = 0.f, s1 = 0.f, s2 = 0.f, s3 = 0.f;
        for (int t = 1 + g; t < T_; t += 16) {
            uint2 v = *(const uint2*)(zb + (size_t)t * P_ + pg * 4);
            s0 += bflo(v.x); s1 += bfhi(v.x);
            s2 += bflo(v.y); s3 += bfhi(v.y);
        }
        part[g][pg * 4 + 0] = s0; part[g][pg * 4 + 1] = s1;
        part[g][pg * 4 + 2] = s2; part[g][pg * 4 + 3] = s3;
        __syncthreads();
        if (tid < 128) {
            float s = 0.f;
            #pragma unroll
            for (int g2 = 0; g2 < 16; g2++) s += part[g2][tid];
            zsum[(size_t)b * P_ + tid] = s;
        }
        return;
    }

    // ---- GRU, 1 batch/block -------------------------------------------------
    _Float16* hbase = (_Float16*)smem;           // [2][264] f16 double buffer

    int lane = tid & 63, w = tid >> 6;
    int col  = lane & 15, quad = lane >> 4;
    int b    = blockIdx.x;
    int jj0  = w * 32 + col;                     // n2=0 gate-col; n2=1 adds 16

    // B fragments: wf[gate][n2][k0] = Wht[gcol][k0*32 + quad*8 .. +7]
    f16x8 wf[3][2][8];
    #pragma unroll
    for (int g = 0; g < 3; g++)
        #pragma unroll
        for (int n2 = 0; n2 < 2; n2++) {
            const _Float16* src = Wht + (size_t)(g * 256 + jj0 + n2 * 16) * 256 + quad * 8;
            #pragma unroll
            for (int k0 = 0; k0 < 8; k0++)
                wf[g][n2][k0] = *(const f16x8*)(src + k0 * 32);
        }
    // pin: asm is the value source -> no in-loop reload/remat (r1: FETCH stayed
    // flat, pin held)
    #pragma unroll
    for (int g = 0; g < 3; g++)
        #pragma unroll
        for (int n2 = 0; n2 < 2; n2++)
            #pragma unroll
            for (int k0 = 0; k0 < 8; k0++)
                asm volatile("" : "+v"(wf[g][n2][k0]));

    for (int i = tid; i < 528; i += 512) hbase[i] = (_Float16)0.f;

    const u16* gb = gi + (size_t)b * T_ * 768;
    u16* cb       = ch + (size_t)b * T_ * 256;
    float bh0 = bhn[jj0], bh1 = bhn[jj0 + 16];
    float hold0 = 0.f, hold1 = 0.f;
    unsigned int pf[2][6];

    {   // preload t=0 gate inputs
        pf[0][0] = gb[jj0];        pf[0][1] = gb[jj0 + 16];
        pf[0][2] = gb[256 + jj0];  pf[0][3] = gb[256 + jj0 + 16];
        pf[0][4] = gb[512 + jj0];  pf[0][5] = gb[512 + jj0 + 16];
    }
    __syncthreads();     // h zeros visible (one-time full drain is fine)

    auto body = [&](int t, int c, int pt) {
        int n = c ^ 1;
        // prefetch gi(t+1) into the other reg set (counted vmcnt, never drained)
        if (pt < T_) {
            const u16* gr = gb + (size_t)pt * 768;
            pf[n][0] = gr[jj0];        pf[n][1] = gr[jj0 + 16];
            pf[n][2] = gr[256 + jj0];  pf[n][3] = gr[256 + jj0 + 16];
            pf[n][4] = gr[512 + jj0];  pf[n][5] = gr[512 + jj0 + 16];
        }
        const _Float16* HC = hbase + c * 264;
        _Float16*       HN = hbase + n * 264;
        // gh = h(t-1) @ Wh : 48 MFMA (3 gates x 2 col-tiles x 8 K-tiles)
        f32x4 aR0 = {}, aR1 = {}, aZ0 = {}, aZ1 = {}, aN0 = {}, aN1 = {};
        #pragma unroll
        for (int k0 = 0; k0 < 8; k0++) {
            f16x8 af = *(const f16x8*)(HC + k0 * 32 + quad * 8);   // broadcast read
            aR0 = __builtin_amdgcn_mfma_f32_16x16x32_f16(af, wf[0][0][k0], aR0, 0, 0, 0);
            aR1 = __builtin_amdgcn_mfma_f32_16x16x32_f16(af, wf[0][1][k0], aR1, 0, 0, 0);
            aZ0 = __builtin_amdgcn_mfma_f32_16x16x32_f16(af, wf[1][0][k0], aZ0, 0, 0, 0);
            aZ1 = __builtin_amdgcn_mfma_f32_16x16x32_f16(af, wf[1][1][k0], aZ1, 0, 0, 0);
            aN0 = __builtin_amdgcn_mfma_f32_16x16x32_f16(af, wf[2][0][k0], aN0, 0, 0, 0);
            aN1 = __builtin_amdgcn_mfma_f32_16x16x32_f16(af, wf[2][1][k0], aN1, 0, 0, 0);
        }
        // all 16 C-rows identical (replicated A) -> element [0] is THE value
        float rg0 = rcpf(1.f + __expf(-(bf2f((u16)pf[c][0]) + aR0[0])));
        float rg1 = rcpf(1.f + __expf(-(bf2f((u16)pf[c][1]) + aR1[0])));
        float zg0 = rcpf(1.f + __expf(-(bf2f((u16)pf[c][2]) + aZ0[0])));
        float zg1 = rcpf(1.f + __expf(-(bf2f((u16)pf[c][3]) + aZ1[0])));
        float xn0 = bf2f((u16)pf[c][4]) + rg0 * (aN0[0] + bh0);
        float xn1 = bf2f((u16)pf[c][5]) + rg1 * (aN1[0] + bh1);
        float nn0 = fmaf(2.f, rcpf(1.f + __expf(-2.f * xn0)), -1.f);
        float nn1 = fmaf(2.f, rcpf(1.f + __expf(-2.f * xn1)), -1.f);
        hold0 = (1.f - zg0) * nn0 + zg0 * hold0;
        hold1 = (1.f - zg1) * nn1 + zg1 * hold1;
        if (quad == 0) {                 // LDS h for next step
            HN[jj0]      = (_Float16)hold0;
            HN[jj0 + 16] = (_Float16)hold1;
        } else if (quad == 1) {          // global ch (redundant copies identical)
            u16* cr = cb + (size_t)t * 256;
            cr[jj0]      = f2bf(hold0);
            cr[jj0 + 16] = f2bf(hold1);
        }
        asm volatile("s_waitcnt lgkmcnt(0)" ::: "memory");
        __builtin_amdgcn_s_barrier();
        asm volatile("" ::: "memory");
    };

    #pragma unroll 1
    for (int t = 0; t < T_; t += 2) {
        body(t,     0, t + 1);
        body(t + 1, 1, t + 2);
    }
}

// ---------------- fused loss, MFMA; 128-row tiles; zh tiles staged in LDS ----
__global__ __launch_bounds__(512) void loss_fused(const u16* __restrict__ ch,
                                                  const u16* __restrict__ Wpt,
                                                  const float* __restrict__ bp,
                                                  const u16* __restrict__ zh,
                                                  const float* __restrict__ zsum,
                                                  float* __restrict__ accum) {
    __shared__ u16 Pst[128][136];
    __shared__ u16 Zt[64][136];
    __shared__ float sS[128];
    __shared__ float red[8];
    int k  = blockIdx.z + 1;
    int b  = blockIdx.y;
    int t0 = blockIdx.x * 128;
    int Tk = T_ - k;
    int tid  = threadIdx.x;
    int w    = tid >> 6;
    int lane = tid & 63;
    int col  = lane & 15;
    int quad = lane >> 4;
    const u16* zb = zh + (size_t)b * T_ * P_;

    // S_bk = zsum_b - sum_{t=1}^{k-1} z[t]
    if (tid < 128) {
        float s = zsum[(size_t)b * P_ + tid];
        for (int t = 1; t < k; t++) s -= bf2f(zb[(size_t)t * P_ + tid]);
        sS[tid] = s;
    }

    // ---- phase 1: Pst = bf16(ch-tile @ Wp[k] + bp[k]) -----------------------
    {
        f32x4 acc[8] = {};
        const u16* arow = ch + ((size_t)b * T_ + t0 + w * 16 + col) * H_;
        const u16* wk   = Wpt + (size_t)(k - 1) * P_ * H_;
        #pragma unroll
        for (int k0 = 0; k0 < 8; k0++) {
            bf16x8 af = *(const bf16x8*)(arow + k0 * 32 + quad * 8);
            #pragma unroll
            for (int nt = 0; nt < 8; nt++) {
                bf16x8 bf = *(const bf16x8*)(wk + (size_t)(nt * 16 + col) * H_ + k0 * 32 + quad * 8);
                acc[nt] = __builtin_amdgcn_mfma_f32_16x16x32_bf16(af, bf, acc[nt], 0, 0, 0);
            }
        }
        #pragma unroll
        for (int nt = 0; nt < 8; nt++) {
            float bias = bp[(size_t)(k - 1) * P_ + nt * 16 + col];
            #pragma unroll
            for (int r = 0; r < 4; r++)
                Pst[w * 16 + quad * 4 + r][nt * 16 + col] = f2bf(acc[nt][r] + bias);
        }
    }
    __syncthreads();

    // ---- phase 2: flash LSE over LDS-staged zh tiles ------------------------
    float mloc[4], sloc[4];
    #pragma unroll
    for (int r = 0; r < 4; r++) { mloc[r] = -INFINITY; sloc[r] = 0.f; }

    for (int ct = 0; ct < Tk; ct += 64) {
        __syncthreads();             // Zt free (prev tile's MFMAs done)
        {
            // 64 rows x 256 B = 16 KB contiguous; 512 thr x 2 x 16 B, coalesced
            int cc = tid;
            #pragma unroll
            for (int rep = 0; rep < 2; rep++, cc += 512) {
                int row = cc >> 4;
                int off = (cc & 15) * 8;
                int tcol = k + ct + row;     // may over-read into slack (masked)
                *(uint4*)&Zt[row][off] = *(const uint4*)(zb + (size_t)tcol * P_ + off);
            }
        }
        __syncthreads();
        f32x4 acc[4] = {};
        #pragma unroll
        for (int k0 = 0; k0 < 4; k0++) {
            bf16x8 af = *(const bf16x8*)(&Pst[w * 16 + col][k0 * 32 + quad * 8]);
            #pragma unroll
            for (int nt = 0; nt < 4; nt++) {
                bf16x8 bf = *(const bf16x8*)(&Zt[nt * 16 + col][k0 * 32 + quad * 8]);
                acc[nt] = __builtin_amdgcn_mfma_f32_16x16x32_bf16(af, bf, acc[nt], 0, 0, 0);
            }
        }
        #pragma unroll
        for (int r = 0; r < 4; r++) {
            float l[4];
            float tmax = -INFINITY;
            #pragma unroll
            for (int nt = 0; nt < 4; nt++) {
                bool valid = (ct + nt * 16 + col) < Tk;
                l[nt] = valid ? acc[nt][r] * INV_TEMP : -INFINITY;
                tmax = fmaxf(tmax, l[nt]);
            }
            float mnew = fmaxf(mloc[r], tmax);
            float e = __expf(l[0] - mnew) + __expf(l[1] - mnew)
                    + __expf(l[2] - mnew) + __expf(l[3] - mnew);
            sloc[r] = sloc[r] * __expf(mloc[r] - mnew) + e;
            mloc[r] = mnew;
        }
    }
    #pragma unroll
    for (int r = 0; r < 4; r++) {
        #pragma unroll
        for (int o = 1; o < 16; o <<= 1) {
            float mo = __shfl_xor(mloc[r], o, 64);
            float so = __shfl_xor(sloc[r], o, 64);
            float mn = fmaxf(mloc[r], mo);
            sloc[r] = sloc[r] * __expf(mloc[r] - mn) + so * __expf(mo - mn);
            mloc[r] = mn;
        }
    }
    float tkinv = INV_TEMP / (float)Tk;
    float scale = 1.0f / ((float)K_ * (float)B_ * (float)Tk);
    float bs = 0.f;
    #pragma unroll
    for (int r = 0; r < 4; r++) {
        int row = w * 16 + quad * 4 + r;
        BF8 pv;
        pv.v = *(const bf16x8*)(&Pst[row][col * 8]);
        float d = 0.f;
        #pragma unroll
        for (int m = 0; m < 8; m++) d = fmaf(bf2f(pv.e[m]), sS[col * 8 + m], d);
        #pragma unroll
        for (int o = 1; o < 16; o <<= 1) d += __shfl_xor(d, o, 64);
        int gr = t0 + row;
        if (gr < Tk) bs += mloc[r] + __logf(sloc[r]) - d * tkinv;
    }
    if (col != 0) bs = 0.f;
    bs = wave_sum(bs);
    if (lane == 0) red[w] = bs;
    __syncthreads();
    if (tid == 0) {
        float tot = 0.f;
        #pragma unroll
        for (int i = 0; i < 8; i++) tot += red[i];
        atomicAdd(&accum[(blockIdx.x * 809 + b * 67 + blockIdx.z * 131) & 1023],
                  tot * scale);
    }
}

__global__ void finalize(const float* __restrict__ accum, float* __restrict__ out) {
    int tid = threadIdx.x;
    __shared__ float red[4];
    float v = 0.f;
    for (int i = tid; i < 1024; i += 256) v += accum[i];
    float sres = wave_sum(v);
    if ((tid & 63) == 0) red[tid >> 6] = sres;
    __syncthreads();
    if (tid == 0) out[0] = red[0] + red[1] + red[2] + red[3];
}

// ---------------- launch -----------------------------------------------------
extern "C" void kernel_launch(void* const* d_in, const int* in_sizes, int n_in,
                              void* d_out, int out_size, void* d_ws, size_t ws_size,
                              hipStream_t stream) {
    const float* x      = (const float*)d_in[0];
    const float* W_enc  = (const float*)d_in[1];
    const float* b_enc  = (const float*)d_in[2];
    const float* W_proj = (const float*)d_in[3];
    const float* b_proj = (const float*)d_in[4];
    const float* Wi     = (const float*)d_in[5];
    const float* bi     = (const float*)d_in[6];
    const float* Wh     = (const float*)d_in[7];
    const float* bhn    = (const float*)d_in[8];
    const float* Wp     = (const float*)d_in[9];
    const float* bp     = (const float*)d_in[10];
    float* out = (float*)d_out;

    // layout (float offsets)
    float* ws    = (float*)d_ws;
    float* bc    = ws;                          // 128
    float* accum = bc + 128;                    // 1024 -> end 1152
    _Float16* Wht = (_Float16*)(ws + 1152);     // 196608 f16 = 98304 fl -> end 99456
    u16* Wct     = (u16*)(ws + 99456);          // 16384 fl -> end 115840
    u16* Wit     = (u16*)(ws + 115840);         // 49152 fl -> end 164992
    u16* Wpt     = (u16*)(ws + 164992);         // 196608 fl -> end 361600
    u16* zh      = (u16*)(ws + 361600);         // 2097152 fl -> end 2458752
    float* zsum  = ws + 2458752;                // 8192 fl (doubles as zh over-read slack) -> end 2466944
    u16* gi      = (u16*)(ws + 2466944);        // 12582912 fl -> end 15049856
    u16* ch      = (u16*)(ws + 15049856);       // 4194304 fl -> end 19244160 (~77 MB)

    const int MT = B_ * T_;                     // 32768

    // merged setup: all weight conversions + fold + accum zero (801 blocks)
    setup_conv<<<801, 256, 0, stream>>>(Wh, Wht, Wi, Wit, Wp, Wpt,
                                        W_enc, b_enc, W_proj, b_proj, Wct, bc, accum);
    // zh = bf16(x @ Wct^T + bc)   (M=32768, N=128, K=256; A converted in-reg)
    gemm_mfma_f32a<<<dim3(1, MT / 64), 256, 0, stream>>>(x, Wct, bc, zh, P_, F_);
    // gi = bf16(zh @ Wit^T + bi)  (M=32768, N=768, K=128)
    gemm_mfma<<<dim3(6, MT / 64), 256, 0, stream>>>(zh, Wit, bi, gi, 3 * H_, P_);
    // GRU scan, MFMA, 1 batch/block (blocks 0..63) + zsum (64..127)
    gru_zsum_kernel<<<GRUB_ + B_, 512, 0, stream>>>(gi, Wht, bhn, ch, zh, zsum);
    // fused pred-GEMM + flash loss (MFMA), 128-row tiles, LDS-staged zh
    loss_fused<<<dim3(4, B_, K_), 512, 0, stream>>>(ch, Wpt, bp, zh, zsum, accum);
    finalize<<<1, 256, 0, stream>>>(accum, out);
}